// Round 10
// baseline (640.162 us; speedup 1.0000x reference)
//
#include <hip/hip_runtime.h>

typedef _Float16 half8 __attribute__((ext_vector_type(8)));
typedef _Float16 half4 __attribute__((ext_vector_type(4)));
typedef float floatx16 __attribute__((ext_vector_type(16)));

constexpr int Bn = 32768, Kn = 4096, Dn = 256;
constexpr int BM = 64;           // rows per block (2 blocks/CU)
constexpr int NCH = 256;         // chunks; chunk = 64 codes x 64 k x {hi|lo} = 16KB

// ---- prep: exact fp32 ||e||^2 + swizzle-baked f16 hi|lo codebook ----
// w16 layout: [code][kc 0..3][256B row: hi 128B | lo 128B]; each row's 16B
// granules XOR-permuted by (code&15) so main-kernel DMA is a linear row copy.
// (Proven R4-R7: absmax=0, SQ_LDS_BANK_CONFLICT=0.)
__global__ void prep_kernel(const float* __restrict__ w, float* __restrict__ esq,
                            char* __restrict__ w16) {
    int code = blockIdx.x * 4 + (threadIdx.x >> 6);
    int l = threadIdx.x & 63;
    float4 v = *reinterpret_cast<const float4*>(w + (size_t)code * Dn + l * 4);
    float s = v.x * v.x + v.y * v.y + v.z * v.z + v.w * v.w;
    #pragma unroll
    for (int off = 32; off; off >>= 1) s += __shfl_xor(s, off);
    if (l == 0) esq[code] = s;

    float fv[4] = {v.x, v.y, v.z, v.w};
    half4 h, lo;
    #pragma unroll
    for (int j = 0; j < 4; ++j) {
        _Float16 hh = (_Float16)fv[j];
        h[j] = hh;
        lo[j] = (_Float16)(fv[j] - (float)hh);
    }
    const int kc = l >> 4;
    const int o_h = (l & 15) * 8;
    const int swz = (code & 15) << 4;
    char* row = w16 + (size_t)code * 1024 + kc * 256;
    *reinterpret_cast<half4*>(row + (o_h ^ swz)) = h;
    *reinterpret_cast<half4*>(row + ((o_h + 128) ^ swz)) = lo;
}

#define GLDS(gsrc, ldsoff)                                                        \
    __builtin_amdgcn_global_load_lds(                                             \
        (const __attribute__((address_space(1))) unsigned int*)(const void*)(gsrc),\
        (__attribute__((address_space(3))) unsigned int*)(void*)(smem + (ldsoff)), \
        16, 0, 0)

#define MFMA(a, b, c) __builtin_amdgcn_mfma_f32_32x32x16_f16((a), (b), (c), 0, 0, 0)

// One phase = one 16KB chunk. Compile-time: KC (a-frag index), B3 (buffer),
// PAR (frag-set parity). Runtime: c_ (chunk id). DMA issue is AFTER the
// barrier: at that barrier every wave has retired its previous-phase lgkm
// wait, so the 3-buffer target's last reads are provably complete.
#define PHASE(CB, J, DO_DMA, DO_READ) do {                                         \
    constexpr int KC = (J) & 3, B3 = (J) % 3, PAR = (J) & 1;                       \
    const int c_ = (CB) + (J);                                                     \
    if (KC == 0) { accA = vzero; accB = vzero; }                                   \
    asm volatile("s_waitcnt vmcnt(0)" ::: "memory");                               \
    __builtin_amdgcn_s_barrier();                                                  \
    asm volatile("" ::: "memory");                                                 \
    if (DO_DMA) {                                                                  \
        const char* s2 = w16 + (size_t)((c_ + 2) >> 2) * 65536 +                   \
                         ((c_ + 2) & 3) * 256 + srcOff0;                           \
        constexpr int BW = ((B3) + 2) % 3;                                         \
        const int d2 = BW * 16384 + dmaDst0;                                       \
        GLDS(s2, d2); GLDS(s2 + 4096, d2 + 1024);                                  \
        GLDS(s2 + 8192, d2 + 2048); GLDS(s2 + 12288, d2 + 3072);                   \
    }                                                                              \
    if (DO_READ) {  /* frags of chunk c_+1 from buf (B3+1)%3 into set PAR^1 */     \
        const char* nb = smem + (((B3) + 1) % 3) * 16384;                          \
        if (PAR == 0) {                                                            \
            _Pragma("unroll")                                                      \
            for (int ks = 0; ks < 4; ++ks) {                                       \
                sh1[ks] = *reinterpret_cast<const half8*>(nb + addrH[ks]);         \
                sl1[ks] = *reinterpret_cast<const half8*>(nb + addrL[ks]);         \
            }                                                                      \
        } else {                                                                   \
            _Pragma("unroll")                                                      \
            for (int ks = 0; ks < 4; ++ks) {                                       \
                sh0[ks] = *reinterpret_cast<const half8*>(nb + addrH[ks]);         \
                sl0[ks] = *reinterpret_cast<const half8*>(nb + addrL[ks]);         \
            }                                                                      \
        }                                                                          \
    }                                                                              \
    __builtin_amdgcn_s_setprio(1);                                                 \
    _Pragma("unroll")                                                              \
    for (int ks = 0; ks < 4; ++ks) {  /* fp16x3: hi*hi | hi*lo + lo*hi */          \
        constexpr int KB = KC * 4;                                                 \
        if (PAR == 0) {                                                            \
            accA = MFMA(a_hi[KB + ks], sh0[ks], accA);                             \
            accB = MFMA(a_hi[KB + ks], sl0[ks], accB);                             \
            accB = MFMA(a_lo[KB + ks], sh0[ks], accB);                             \
        } else {                                                                   \
            accA = MFMA(a_hi[KB + ks], sh1[ks], accA);                             \
            accB = MFMA(a_hi[KB + ks], sl1[ks], accB);                             \
            accB = MFMA(a_lo[KB + ks], sh1[ks], accB);                             \
        }                                                                          \
    }                                                                              \
    __builtin_amdgcn_s_setprio(0);                                                 \
    if (KC == 3) {  /* per-tile argmin; ascending tile + strict < = 1st occur */   \
        const int tile_ = c_ >> 2;                                                 \
        const float e = esqf[tile_ * 64 + nw * 32 + ll];                           \
        _Pragma("unroll")                                                          \
        for (int q = 0; q < 16; ++q) {                                             \
            const float v = fmaf(-2.f, accA[q], fmaf(-2.f, accB[q], e));           \
            const int sh = (q & 3) * 8;                                            \
            if (v < rbv[q]) {                                                      \
                rbv[q] = v;                                                        \
                rbn[q >> 2] = (rbn[q >> 2] & ~(255u << sh)) |                      \
                              ((unsigned)tile_ << sh);                             \
            }                                                                      \
        }                                                                          \
    }                                                                              \
} while (0)

// 4 waves (2M x 2N), M=32 rows/wave, BM=64 -> grid 512 = 2 blocks/CU.
// LDS map: bufs 3x16384 [0,49152) | esq [49152,65536) | comb [65536,66560) | idxF [66560,66816)
__global__ void
__launch_bounds__(256, 2)
vq_kernel(const float* __restrict__ z, const float* __restrict__ w,
          const float* __restrict__ esq, const char* __restrict__ w16,
          float* __restrict__ out0, float* __restrict__ out1,
          float* __restrict__ out2) {
    __shared__ char smem[66816];
    const int tid = threadIdx.x;
    const int wv = tid >> 6, l = tid & 63;
    const int mw = wv >> 1, nw = wv & 1;       // 2 M-waves (32 rows) x 2 N-halves (32 cols)
    const int lh = l >> 5, ll = l & 31;
    const int blkRow = blockIdx.x * BM;

    // esq -> LDS (16KB) before the vmcnt(0) regime starts
    float* esqf = reinterpret_cast<float*>(smem + 49152);
    {
        float4* es4 = reinterpret_cast<float4*>(esqf);
        const float4* eg4 = reinterpret_cast<const float4*>(esq);
        #pragma unroll
        for (int j = 0; j < 4; ++j) es4[j * 256 + tid] = eg4[j * 256 + tid];
    }

    // A: 32 z-rows per wave as f16 hi/lo (128 regs). lane: row=ll, k=ks*16+lh*8+j
    half8 a_hi[16], a_lo[16];
    {
        const float* zr = z + (size_t)(blkRow + mw * 32 + ll) * Dn + lh * 8;
        #pragma unroll
        for (int ks = 0; ks < 16; ++ks) {
            float4 f0 = *reinterpret_cast<const float4*>(zr + ks * 16);
            float4 f1 = *reinterpret_cast<const float4*>(zr + ks * 16 + 4);
            float fv[8] = {f0.x, f0.y, f0.z, f0.w, f1.x, f1.y, f1.z, f1.w};
            #pragma unroll
            for (int j = 0; j < 8; ++j) {
                _Float16 h = (_Float16)fv[j];
                a_hi[ks][j] = h;
                a_lo[ks][j] = (_Float16)(fv[j] - (float)h);
            }
        }
    }

    // DMA: wave stages 4KB/chunk as 4 linear 1KB row-copies.
    // local code lc = wv*16 + j*4 + (l>>4); per-lane src byte (l&15)*16; dest base uniform.
    const size_t srcOff0 = (size_t)(wv * 16 + (l >> 4)) * 1024 + (l & 15) * 16;
    const int dmaDst0 = wv * 4096;

    // ds_read addrs (swizzled), col c_loc = nw*32 + ll
    int addrH[4], addrL[4];
    {
        const int c_loc = nw * 32 + ll;
        const int swz = (c_loc & 15) << 4;
        #pragma unroll
        for (int ks = 0; ks < 4; ++ks) {
            const int o = ks * 32 + lh * 16;
            addrH[ks] = c_loc * 256 + (o ^ swz);
            addrL[ks] = c_loc * 256 + ((o + 128) ^ swz);
        }
    }

    const floatx16 vzero = {};
    floatx16 accA = vzero, accB = vzero;
    float rbv[16];
    unsigned rbn[4] = {0, 0, 0, 0};
    #pragma unroll
    for (int q = 0; q < 16; ++q) rbv[q] = 3.4e38f;

    half8 sh0[4], sl0[4], sh1[4], sl1[4];

    asm volatile("s_waitcnt vmcnt(0)" ::: "memory");
    __syncthreads();   // esq staged + A loads drained

    // prologue: DMA chunks 0 (buf0), 1 (buf1); then frags of chunk 0 -> set0
    GLDS(w16 + srcOff0, dmaDst0);
    GLDS(w16 + 4096 + srcOff0, dmaDst0 + 1024);
    GLDS(w16 + 8192 + srcOff0, dmaDst0 + 2048);
    GLDS(w16 + 12288 + srcOff0, dmaDst0 + 3072);
    GLDS(w16 + 256 + srcOff0, 16384 + dmaDst0);
    GLDS(w16 + 256 + 4096 + srcOff0, 16384 + dmaDst0 + 1024);
    GLDS(w16 + 256 + 8192 + srcOff0, 16384 + dmaDst0 + 2048);
    GLDS(w16 + 256 + 12288 + srcOff0, 16384 + dmaDst0 + 3072);
    asm volatile("s_waitcnt vmcnt(0)" ::: "memory");
    __builtin_amdgcn_s_barrier();
    asm volatile("" ::: "memory");
    #pragma unroll
    for (int ks = 0; ks < 4; ++ks) {
        sh0[ks] = *reinterpret_cast<const half8*>(smem + addrH[ks]);
        sl0[ks] = *reinterpret_cast<const half8*>(smem + addrL[ks]);
    }

    // main: 21 x 12 phases (kc mod4, buf mod3, parity mod2 all compile-time)
    for (int cb = 0; cb < 252; cb += 12) {
        PHASE(cb, 0, 1, 1);  PHASE(cb, 1, 1, 1);  PHASE(cb, 2, 1, 1);
        PHASE(cb, 3, 1, 1);  PHASE(cb, 4, 1, 1);  PHASE(cb, 5, 1, 1);
        PHASE(cb, 6, 1, 1);  PHASE(cb, 7, 1, 1);  PHASE(cb, 8, 1, 1);
        PHASE(cb, 9, 1, 1);  PHASE(cb, 10, 1, 1); PHASE(cb, 11, 1, 1);
    }
    // tail: chunks 252..255 (252 % 12 == 0 so J=0..3 keeps the same pattern)
    PHASE(252, 0, 1, 1);
    PHASE(252, 1, 1, 1);
    PHASE(252, 2, 0, 1);
    PHASE(252, 3, 0, 0);

    // final per-row argmin: unpack tile -> col, lexicographic shfl reduce (32-lane half)
    int2* comb = reinterpret_cast<int2*>(smem + 65536);   // [64 rows][2 nw]
    #pragma unroll
    for (int q = 0; q < 16; ++q) {
        float v = rbv[q];
        int i = (int)((rbn[q >> 2] >> ((q & 3) * 8)) & 255u) * 64 + nw * 32 + ll;
        #pragma unroll
        for (int off = 1; off < 32; off <<= 1) {
            float ov = __shfl_xor(v, off);
            int oi = __shfl_xor(i, off);
            if (ov < v || (ov == v && oi < i)) { v = ov; i = oi; }
        }
        if (ll == 0) {   // m74 C-layout: row = (q&3) + 8*(q>>2) + 4*lh
            const int r32 = (q & 3) + 8 * (q >> 2) + 4 * lh;
            comb[(mw * 32 + r32) * 2 + nw] = make_int2(__float_as_int(v), i);
        }
    }
    __syncthreads();
    int* idxF = reinterpret_cast<int*>(smem + 66560);
    if (tid < 64) {
        int2 c0 = comb[tid * 2], c1 = comb[tid * 2 + 1];
        float v0 = __int_as_float(c0.x), v1 = __int_as_float(c1.x);
        idxF[tid] = (v1 < v0 || (v1 == v0 && c1.y < c0.y)) ? c1.y : c0.y;
    }
    __syncthreads();

    // gather: out0 = z + (q - z) (ref's exact fp32 expr), out1 = q, out2 = idx
    {
        const int r = tid >> 2, p4 = tid & 3;
        const int gRow = blkRow + r;
        const int idx = idxF[r];
        const float* wr = w + (size_t)idx * Dn + p4 * 64;
        const float* zr = z + (size_t)gRow * Dn + p4 * 64;
        float* o0 = out0 + (size_t)gRow * Dn + p4 * 64;
        float* o1 = out1 + (size_t)gRow * Dn + p4 * 64;
        #pragma unroll
        for (int q = 0; q < 16; ++q) {
            float4 wq = *reinterpret_cast<const float4*>(wr + q * 4);
            float4 zq = *reinterpret_cast<const float4*>(zr + q * 4);
            *reinterpret_cast<float4*>(o1 + q * 4) = wq;
            float4 sg;
            sg.x = zq.x + (wq.x - zq.x);
            sg.y = zq.y + (wq.y - zq.y);
            sg.z = zq.z + (wq.z - zq.z);
            sg.w = zq.w + (wq.w - zq.w);
            *reinterpret_cast<float4*>(o0 + q * 4) = sg;
        }
        if (p4 == 0) out2[gRow] = (float)idx;
    }
}

extern "C" void kernel_launch(void* const* d_in, const int* in_sizes, int n_in,
                              void* d_out, int out_size, void* d_ws, size_t ws_size,
                              hipStream_t stream) {
    (void)in_sizes; (void)n_in; (void)out_size; (void)ws_size;
    const float* z = (const float*)d_in[0];
    const float* w = (const float*)d_in[1];
    float* esq = (float*)d_ws;                        // 16 KB
    char* w16 = (char*)d_ws + 16384;                  // 4 MB swizzle-baked hi|lo codebook
    float* out0 = (float*)d_out;
    float* out1 = out0 + (size_t)Bn * Dn;
    float* out2 = out1 + (size_t)Bn * Dn;

    prep_kernel<<<Kn / 4, 256, 0, stream>>>(w, esq, w16);
    vq_kernel<<<Bn / BM, 256, 0, stream>>>(z, w, esq, w16, out0, out1, out2);
}